// Round 14
// baseline (1913.728 us; speedup 1.0000x reference)
//
#include <hip/hip_runtime.h>
#include <cstdint>
#include <cstddef>

#define VV 18000
#define HH 400
#define H3 1200
#define H3P 1280
#define KP 416
#define BB 16
#define TE 256
#define SS 30
#define TDN 8
#define GGN 3
#define SBN 480
#define NROW_ENC 4096
#define VP 18048
#define MP_DEC 512

#define EBLK 25          // enc blocks per direction
#define GI_TILES 320     // (4096/128) x (1280/128) per direction
#define GIDEC_TILES 300  // (3840/128) x (1280/128)
#define EMBB_BLKS 256

typedef __bf16 bf16;
typedef __attribute__((ext_vector_type(8))) __bf16 bf16x8;
typedef __attribute__((ext_vector_type(4))) float f32x4;
typedef __attribute__((ext_vector_type(4))) unsigned int u32x4;

static __device__ __forceinline__ float sigf(float x) {
    return 1.0f / (1.0f + __expf(-x));
}

// ---------------- GEMM tile body. cmode: 0 = f32 plain, 1 = bf16 plain, 2 = f32 sc0sc1.
static __device__ void gemm_dev(const bf16* __restrict__ A, const bf16* __restrict__ B,
                                float* __restrict__ Cf, bf16* __restrict__ Ch,
                                int M, int N, int K, int m0, int n0, int cmode) {
    __shared__ __align__(16) bf16 sA[128 * 32];
    __shared__ __align__(16) bf16 sB[128 * 32];
    const int tid = threadIdx.x;
    const int lane = tid & 63;
    const int wave = tid >> 6;
    const int wm = wave >> 1, wn = wave & 1;
    f32x4 acc[4][4] = {};
    const int c0 = tid, c1 = tid + 256;
    const int r0 = c0 >> 2, q0 = (c0 & 3) * 8;
    const int r1 = c1 >> 2, q1 = (c1 & 3) * 8;
    const int ar = lane & 15, ak = (lane >> 4) * 8;
    const int nk = K >> 5;
    for (int kt = 0; kt < nk; ++kt) {
        const int kb = kt * 32;
        uint4 a0 = *(const uint4*)(A + (size_t)(m0 + r0) * K + kb + q0);
        uint4 a1 = *(const uint4*)(A + (size_t)(m0 + r1) * K + kb + q1);
        uint4 b0 = *(const uint4*)(B + (size_t)(n0 + r0) * K + kb + q0);
        uint4 b1 = *(const uint4*)(B + (size_t)(n0 + r1) * K + kb + q1);
        __syncthreads();
        *(uint4*)(sA + r0 * 32 + q0) = a0;
        *(uint4*)(sA + r1 * 32 + q1) = a1;
        *(uint4*)(sB + r0 * 32 + q0) = b0;
        *(uint4*)(sB + r1 * 32 + q1) = b1;
        __syncthreads();
        bf16x8 af[4], bg[4];
#pragma unroll
        for (int i = 0; i < 4; ++i)
            af[i] = *(const bf16x8*)(sA + (wm * 64 + i * 16 + ar) * 32 + ak);
#pragma unroll
        for (int j = 0; j < 4; ++j)
            bg[j] = *(const bf16x8*)(sB + (wn * 64 + j * 16 + ar) * 32 + ak);
#pragma unroll
        for (int i = 0; i < 4; ++i)
#pragma unroll
            for (int j = 0; j < 4; ++j)
                acc[i][j] = __builtin_amdgcn_mfma_f32_16x16x32_bf16(af[i], bg[j], acc[i][j], 0, 0, 0);
    }
    const int cr = (lane >> 4) * 4, cc = lane & 15;
#pragma unroll
    for (int i = 0; i < 4; ++i)
#pragma unroll
        for (int j = 0; j < 4; ++j)
#pragma unroll
            for (int q = 0; q < 4; ++q) {
                int row = m0 + wm * 64 + i * 16 + cr + q;
                int col = n0 + wn * 64 + j * 16 + cc;
                float v = acc[i][j][q];
                if (cmode == 1) {
                    Ch[(size_t)row * N + col] = (bf16)v;
                } else if (cmode == 2) {
                    float* p = Cf + (size_t)row * N + col;
                    asm volatile("global_store_dword %0, %1, off sc0 sc1"
                                 :: "v"(p), "v"(v) : "memory");
                } else {
                    Cf[(size_t)row * N + col] = v;
                }
            }
}

__global__ __launch_bounds__(256) void gemm_bt(const bf16* __restrict__ A,
                                               const bf16* __restrict__ B,
                                               float* __restrict__ Cf, bf16* __restrict__ Ch,
                                               int M, int N, int K, int cmode) {
    gemm_dev(A, B, Cf, Ch, M, N, K, blockIdx.x * 128, blockIdx.y * 128, cmode);
}

// ---------------- consolidated prep: all padded bf16 staging in one launch ----------------
__global__ void prep_all(const int* __restrict__ story, const int* __restrict__ target,
                         const float* __restrict__ emb, const float* __restrict__ slot,
                         const float* __restrict__ wih_f, const float* __restrict__ wih_b,
                         const float* __restrict__ dwih, const float* __restrict__ dwhh,
                         bf16* __restrict__ aenc,
                         bf16* __restrict__ wfb, bf16* __restrict__ wbb,
                         bf16* __restrict__ dwihb, bf16* __restrict__ dwhhb,
                         float* __restrict__ decxf, bf16* __restrict__ decxb,
                         bf16* __restrict__ h2ball) {
    const size_t gid = (size_t)blockIdx.x * blockDim.x + threadIdx.x;
    const size_t gs = (size_t)gridDim.x * blockDim.x;
    // aenc
    for (size_t i = gid; i < (size_t)NROW_ENC * KP; i += gs) {
        int m = (int)(i / KP), k = (int)(i % KP);
        int t = m >> 4, b = m & 15;
        float v = 0.f;
        if (k < HH) v = emb[(size_t)story[b * TE + t] * HH + k];
        aenc[i] = (bf16)v;
    }
    // weight pads
    for (size_t i = gid; i < (size_t)H3P * KP; i += gs) {
        int r = (int)(i / KP), c = (int)(i % KP);
        bool in = (r < H3 && c < HH);
        wfb[i]   = (bf16)(in ? wih_f[(size_t)r * HH + c] : 0.f);
        wbb[i]   = (bf16)(in ? wih_b[(size_t)r * HH + c] : 0.f);
        dwihb[i] = (bf16)(in ? dwih[(size_t)r * HH + c] : 0.f);
        dwhhb[i] = (bf16)(in ? dwhh[(size_t)r * HH + c] : 0.f);
    }
    // decoder inputs
    for (size_t i = gid; i < (size_t)TDN * SBN * KP; i += gs) {
        int k = (int)(i % KP);
        int nn = (int)(i / KP);
        int n = nn % SBN;
        int td = nn / SBN;
        int s = n >> 4, b = n & 15;
        float v = 0.f;
        if (k < HH) {
            if (td == 0) v = slot[s * HH + k];
            else v = emb[(size_t)target[(b * SS + s) * TDN + (td - 1)] * HH + k];
            decxf[((size_t)td * SBN + n) * HH + k] = v;
        }
        decxb[i] = (bf16)v;
    }
    // h2ball zero
    for (size_t i = gid; i < (size_t)9 * MP_DEC * KP; i += gs) h2ball[i] = (bf16)0.f;
}

// ---------------- fat encoder v2 ----------------
// blocks [0,50): recurrence; [50,690): gi GEMM tiles (320/dir, sc0sc1 C + flags);
// [690,990): gidec tiles; [990,1246): embb prep.
__global__ __launch_bounds__(256) void enc_fat(
    float* __restrict__ gif, float* __restrict__ gib,
    const float* __restrict__ whh_f, const float* __restrict__ whh_b,
    const float* __restrict__ bih_f, const float* __restrict__ bhh_f,
    const float* __restrict__ bih_b, const float* __restrict__ bhh_b,
    float* __restrict__ hist_f, float* __restrict__ hist_b,
    unsigned int* __restrict__ hbuf_f, unsigned int* __restrict__ hbuf_b,
    unsigned int* __restrict__ flags, unsigned int* __restrict__ gflags,
    const bf16* __restrict__ aenc, const bf16* __restrict__ wfb, const bf16* __restrict__ wbb,
    const bf16* __restrict__ decxb, const bf16* __restrict__ dwihb,
    float* __restrict__ gidec,
    const float* __restrict__ emb, bf16* __restrict__ embb) {
    const int bid = blockIdx.x;
    const int tid = threadIdx.x;

    if (bid >= 2 * EBLK) {
        int hb = bid - 2 * EBLK;
        if (hb < 2 * GI_TILES) {
            // gi tile: consumption-ordered (fwd ascending mrow, bwd descending)
            const int dir = hb >= GI_TILES;
            int t = hb - dir * GI_TILES;
            const int mrow = dir ? (31 - t / 10) : (t / 10);
            const int ncol = t % 10;
            gemm_dev(aenc, dir ? wbb : wfb, dir ? gib : gif, nullptr,
                     NROW_ENC, H3P, KP, mrow * 128, ncol * 128, /*cmode=*/2);
            asm volatile("s_waitcnt vmcnt(0)" ::: "memory");
            __syncthreads();
            if (tid == 0) {
                unsigned one = 1u;
                unsigned* fw = gflags + ((size_t)dir * 32 + mrow) * 16 + ncol;
                asm volatile("global_store_dword %0, %1, off sc0 sc1"
                             :: "v"(fw), "v"(one) : "memory");
            }
        } else if (hb < 2 * GI_TILES + GIDEC_TILES) {
            int t = hb - 2 * GI_TILES;
            gemm_dev(decxb, dwihb, gidec, nullptr, TDN * SBN, H3P, KP,
                     (t % 30) * 128, (t / 30) * 128, /*cmode=*/0);
        } else {
            const size_t total = (size_t)VP * KP;
            size_t idx = (size_t)(hb - 2 * GI_TILES - GIDEC_TILES) * 256 + tid;
            const size_t stride = (size_t)EMBB_BLKS * 256;
            for (; idx < total; idx += stride) {
                int r = (int)(idx / KP), c = (int)(idx % KP);
                float v = (r < VV && c < HH) ? emb[(size_t)r * HH + c] : 0.f;
                embb[idx] = (bf16)v;
            }
        }
        return;
    }

    // -------- encoder recurrence --------
    const int dir = bid & 1;
    const int blk = bid >> 1;
    const int j0 = blk * 16;
    const float* gi  = dir ? gib : gif;
    const float* whh = dir ? whh_b : whh_f;
    const float* bih = dir ? bih_b : bih_f;
    const float* bhh = dir ? bhh_b : bhh_f;
    float* hist = dir ? hist_b : hist_f;
    unsigned int* hbuf = dir ? hbuf_b : hbuf_f;

    __shared__ float GHL[3 * 256];

    const int wv = tid >> 6, lane = tid & 63;
    const int ub = tid >> 4, ucol = tid & 15;
    const int uj = j0 + ucol;
    const float bihr = bih[uj], bihz = bih[HH + uj], bihg = bih[2 * HH + uj];
    const float bhhr = bhh[uj], bhhz = bhh[HH + uj], bhhg = bhh[2 * HH + uj];
    // the 3 gi N-tiles this block reads (16-col groups never straddle 128 boundaries)
    const int c0t = (j0) >> 7, c1t = (400 + j0) >> 7, c2t = (800 + j0) >> 7;

    const int kk0 = (lane >> 4) * 8;
    bf16x8 Bf[13];
    if (wv < 3) {
        const int brow = wv * HH + j0 + (lane & 15);
#pragma unroll
        for (int ks = 0; ks < 13; ++ks) {
            bf16x8 v;
#pragma unroll
            for (int e = 0; e < 8; ++e) {
                int k = kk0 + ks * 32 + e;
                v[e] = (k < HH) ? (bf16)whh[(size_t)brow * HH + k] : (bf16)0.f;
            }
            Bf[ks] = v;
        }
    }

    union UV { unsigned int d[4]; bf16x8 v; };

    float hp = 0.f;
    int gwm = -1;   // gi tile-row watermark (polled once per mrow)

    for (int s = 0; s < TE; ++s) {
        const int tt = dir ? (TE - 1 - s) : s;
        const int mrow = tt >> 3;
        if (mrow != gwm) {
            gwm = mrow;
            if (wv == 0) {
                const unsigned* gf = gflags + ((size_t)dir * 32 + mrow) * 16;
                while (true) {
                    unsigned f = 1u;
                    if (lane < 3) {
                        const unsigned* ga = gf + (lane == 0 ? c0t : lane == 1 ? c1t : c2t);
                        asm volatile("global_load_dword %0, %1, off sc0 sc1"
                                     : "=v"(f) : "v"(ga));
                    }
                    asm volatile("s_waitcnt vmcnt(0)" ::: "memory");
                    if (__all((int)(f != 0u))) break;
                }
            }
            __syncthreads();
        }
        const float* gir = gi + ((size_t)tt * BB + ub) * H3P;
        float gi0 = gir[uj];
        float gi1 = gir[HH + uj];
        float gi2 = gir[2 * HH + uj];

        f32x4 acc0 = {}, acc1 = {};
        if (s > 0) {
            if (wv == 0) {
                const unsigned int* fl = flags + ((size_t)dir * TE + (s - 1)) * 32;
                while (true) {
                    unsigned f = 1u;
                    if (lane < EBLK)
                        asm volatile("global_load_dword %0, %1, off sc0 sc1"
                                     : "=v"(f) : "v"(fl + lane));
                    asm volatile("s_waitcnt vmcnt(0)" ::: "memory");
                    if (__all((int)(f != 0u))) break;
                }
            }
            __syncthreads();
            if (wv < 3) {
                const int ttp = dir ? (tt + 1) : (tt - 1);
                const unsigned int* hrow =
                    hbuf + ((size_t)ttp * BB + (lane & 15)) * KP + kk0;
                u32x4 ua[13], ubv[13];
#pragma unroll
                for (int ks = 0; ks < 13; ++ks) {
                    asm volatile("global_load_dwordx4 %0, %1, off offset:%c2 sc0 sc1"
                                 : "=v"(ua[ks]) : "v"(hrow), "n"(ks * 128));
                    asm volatile("global_load_dwordx4 %0, %1, off offset:%c2 sc0 sc1"
                                 : "=v"(ubv[ks]) : "v"(hrow), "n"(ks * 128 + 16));
                }
                asm volatile("s_waitcnt vmcnt(0)" ::: "memory");
                __builtin_amdgcn_sched_barrier(0);
#pragma unroll
                for (int ks = 0; ks < 13; ++ks) {
                    u32x4 a = ua[ks], b = ubv[ks];
                    UV ah, al;
                    ah.d[0] = (a.x & 0xffffu) | (a.y << 16);
                    ah.d[1] = (a.z & 0xffffu) | (a.w << 16);
                    ah.d[2] = (b.x & 0xffffu) | (b.y << 16);
                    ah.d[3] = (b.z & 0xffffu) | (b.w << 16);
                    al.d[0] = (a.x >> 16) | (a.y & 0xffff0000u);
                    al.d[1] = (a.z >> 16) | (a.w & 0xffff0000u);
                    al.d[2] = (b.x >> 16) | (b.y & 0xffff0000u);
                    al.d[3] = (b.z >> 16) | (b.w & 0xffff0000u);
                    acc0 = __builtin_amdgcn_mfma_f32_16x16x32_bf16(ah.v, Bf[ks], acc0, 0, 0, 0);
                    acc1 = __builtin_amdgcn_mfma_f32_16x16x32_bf16(al.v, Bf[ks], acc1, 0, 0, 0);
                }
            }
        }
        if (wv < 3) {
            f32x4 at = acc0 + acc1;
            const int cb0 = wv * 256 + ((lane >> 4) * 4) * 16 + (lane & 15);
            GHL[cb0]      = at[0];
            GHL[cb0 + 16] = at[1];
            GHL[cb0 + 32] = at[2];
            GHL[cb0 + 48] = at[3];
        }
        __syncthreads();

        float ghr = GHL[tid];
        float ghz = GHL[256 + tid];
        float ghg = GHL[512 + tid];
        float r = sigf(gi0 + bihr + ghr + bhhr);
        float z = sigf(gi1 + bihz + ghz + bhhz);
        float g = tanhf(gi2 + bihg + r * (ghg + bhhg));
        float hn = (1.f - z) * g + z * hp;
        hp = hn;
        hist[((size_t)tt * BB + ub) * HH + uj] = hn;
        bf16 hi = (bf16)hn;
        bf16 lo = (bf16)(hn - (float)hi);
        unsigned int pk = (unsigned int)__builtin_bit_cast(unsigned short, hi)
                        | ((unsigned int)__builtin_bit_cast(unsigned short, lo) << 16);
        unsigned int* hw = hbuf + ((size_t)tt * BB + ub) * KP + uj;
        asm volatile("global_store_dword %0, %1, off sc0 sc1" :: "v"(hw), "v"(pk) : "memory");

        asm volatile("s_waitcnt vmcnt(0)" ::: "memory");
        __syncthreads();
        if (tid == 0) {
            unsigned int one = 1u;
            unsigned int* fw = flags + ((size_t)dir * TE + s) * 32 + blk;
            asm volatile("global_store_dword %0, %1, off sc0 sc1" :: "v"(fw), "v"(one) : "memory");
        }
    }
}

// combine_enc + init_hdec2 merged
__global__ void combine_init(const float* __restrict__ hf, const float* __restrict__ hb,
                             float* __restrict__ enc_out,
                             float* __restrict__ hdec, bf16* __restrict__ h2b) {
    const size_t gid = (size_t)blockIdx.x * blockDim.x + threadIdx.x;
    const size_t gs = (size_t)gridDim.x * blockDim.x;
    for (size_t i = gid; i < (size_t)BB * TE * HH; i += gs) {
        int hcol = (int)(i % HH);
        int t = (int)((i / HH) % TE);
        int b = (int)(i / (HH * TE));
        size_t src = ((size_t)t * BB + b) * HH + hcol;
        enc_out[i] = hf[src] + hb[src];
    }
    for (size_t i = gid; i < (size_t)SBN * HH; i += gs) {
        int hcol = (int)(i % HH);
        int n = (int)(i / HH);
        int b = n & 15;
        float v = hf[((size_t)(TE - 1) * BB + b) * HH + hcol] + hb[((size_t)b) * HH + hcol];
        hdec[i] = v;
        h2b[(size_t)n * KP + hcol] = (bf16)v;
    }
}

__global__ void gru_dec2(const float* __restrict__ gi, const float* __restrict__ gh,
                         const float* __restrict__ bih, const float* __restrict__ bhh,
                         const float* __restrict__ hprev, float* __restrict__ hnew,
                         bf16* __restrict__ h2b) {
    int idx = blockIdx.x * blockDim.x + threadIdx.x;
    if (idx >= SBN * HH) return;
    int n = idx / HH, j = idx % HH;
    const float* gir = gi + (size_t)n * H3P;
    const float* ghr = gh + (size_t)n * H3P;
    float r = sigf(gir[j] + bih[j] + ghr[j] + bhh[j]);
    float z = sigf(gir[HH + j] + bih[HH + j] + ghr[HH + j] + bhh[HH + j]);
    float g = tanhf(gir[2 * HH + j] + bih[2 * HH + j] + r * (ghr[2 * HH + j] + bhh[2 * HH + j]));
    float hn = (1.f - z) * g + z * hprev[idx];
    hnew[idx] = hn;
    h2b[(size_t)n * KP + j] = (bf16)hn;
}

// ---------------- bulk attention (unchanged) ----------------
__global__ __launch_bounds__(256) void attn3(
    const float* __restrict__ hfall,
    const float* __restrict__ enc,
    const float* __restrict__ decxf,
    const float* __restrict__ Wr, const float* __restrict__ br,
    const float* __restrict__ Wg, const float* __restrict__ bg,
    float* __restrict__ probw,
    float* __restrict__ sww,
    float* __restrict__ outg) {
    const int b = blockIdx.x >> 1;
    const int half = blockIdx.x & 1;
    const int td = blockIdx.y;
    const int s0 = half * 15;
    const int tid = threadIdx.x;
    const int lane = tid & 63, wv = tid >> 6;

    __shared__ __align__(16) float h2L[15][HH];
    __shared__ __align__(16) float scL[15][TE];
    __shared__ __align__(16) float cxL[15][HH];

    const float* h2base = hfall + (size_t)(td + 1) * SBN * HH;
    for (int i = tid; i < 15 * HH; i += 256) {
        int j = i / HH, k = i % HH;
        int n = (s0 + j) * BB + b;
        h2L[j][k] = h2base[(size_t)n * HH + k];
    }
    __syncthreads();

    {
        float acc[15];
#pragma unroll
        for (int j = 0; j < 15; ++j) acc[j] = 0.f;
        const float4* er = (const float4*)(enc + ((size_t)b * TE + tid) * HH);
        for (int k4 = 0; k4 < HH / 4; ++k4) {
            float4 e = er[k4];
#pragma unroll
            for (int j = 0; j < 15; ++j) {
                float4 hv = *(const float4*)(&h2L[j][k4 * 4]);
                acc[j] += e.x * hv.x + e.y * hv.y + e.z * hv.z + e.w * hv.w;
            }
        }
#pragma unroll
        for (int j = 0; j < 15; ++j) scL[j][tid] = acc[j];
    }
    __syncthreads();

    for (int j = wv; j < 15; j += 4) {
        float v0 = scL[j][lane], v1 = scL[j][lane + 64];
        float v2 = scL[j][lane + 128], v3 = scL[j][lane + 192];
        float m = fmaxf(fmaxf(v0, v1), fmaxf(v2, v3));
        for (int d = 32; d; d >>= 1) m = fmaxf(m, __shfl_xor(m, d));
        v0 = __expf(v0 - m); v1 = __expf(v1 - m);
        v2 = __expf(v2 - m); v3 = __expf(v3 - m);
        float s = v0 + v1 + v2 + v3;
        for (int d = 32; d; d >>= 1) s += __shfl_xor(s, d);
        float inv = 1.f / s;
        scL[j][lane]       = v0 * inv;
        scL[j][lane + 64]  = v1 * inv;
        scL[j][lane + 128] = v2 * inv;
        scL[j][lane + 192] = v3 * inv;
    }
    __syncthreads();

    for (int i = tid; i < 15 * TE; i += 256) {
        int j = i / TE, t = i % TE;
        int n = (s0 + j) * BB + b;
        probw[((size_t)td * SBN + n) * TE + t] = scL[j][t];
    }

    {
        float cx0[15], cx1[15];
#pragma unroll
        for (int j = 0; j < 15; ++j) { cx0[j] = 0.f; cx1[j] = 0.f; }
        const int c0 = tid, c1 = tid + 256;
        const bool has2 = (c1 < HH);
        for (int t = 0; t < TE; t += 2) {
            const float* e0r = enc + ((size_t)b * TE + t) * HH;
            const float* e1r = e0r + HH;
            float e00 = e0r[c0], e01 = e1r[c0];
            float e10 = 0.f, e11 = 0.f;
            if (has2) { e10 = e0r[c1]; e11 = e1r[c1]; }
#pragma unroll
            for (int j = 0; j < 15; ++j) {
                float2 p = *(const float2*)(&scL[j][t]);
                cx0[j] += p.x * e00 + p.y * e01;
                cx1[j] += p.x * e10 + p.y * e11;
            }
        }
#pragma unroll
        for (int j = 0; j < 15; ++j) {
            cxL[j][c0] = cx0[j];
            if (has2) cxL[j][c1] = cx1[j];
        }
    }
    __syncthreads();

    for (int j = wv; j < 15; j += 4) {
        int n = (s0 + j) * BB + b;
        const float* dx = decxf + ((size_t)td * SBN + n) * HH;
        float a = 0.f;
        for (int k = lane; k < H3; k += 64) {
            float v = (k < HH) ? h2L[j][k]
                    : (k < 2 * HH) ? cxL[j][k - HH]
                    : dx[k - 2 * HH];
            a += v * Wr[k];
        }
        for (int d = 32; d; d >>= 1) a += __shfl_xor(a, d);
        if (lane == 0) sww[(size_t)td * SBN + n] = sigf(a + br[0]);
    }

    if (td == 0) {
        for (int j = wv; j < 15; j += 4) {
            int n = (s0 + j) * BB + b;
#pragma unroll
            for (int g = 0; g < GGN; ++g) {
                float a = 0.f;
                for (int k = lane; k < HH; k += 64) a += cxL[j][k] * Wg[g * HH + k];
                for (int d = 32; d; d >>= 1) a += __shfl_xor(a, d);
                if (lane == 0) outg[n * GGN + g] = a + bg[g];
            }
        }
    }
}

// softmax over vocab (bf16 logits) + final write + fused pointer scatter.
__global__ __launch_bounds__(1024) void smax_scatter3(
    const bf16* __restrict__ logitsH, const float* __restrict__ sw,
    const int* __restrict__ story, const float* __restrict__ probw,
    float* __restrict__ out, int td0) {
    int n = blockIdx.x, tid = threadIdx.x;
    int td = td0 + blockIdx.y;
    const bf16* lrow = logitsH + ((size_t)blockIdx.y * MP_DEC + n) * VP;
    const float* prow = probw + ((size_t)td * SBN + n) * TE;
    float swv = sw[(size_t)td * SBN + n];
    __shared__ float red[16];
    __shared__ float bc[2];
    float v[18];
    float mx = -1e30f;
#pragma unroll
    for (int i = 0; i < 18; ++i) {
        int c = tid + (i << 10);
        v[i] = (c < VV) ? (float)lrow[c] : -1e30f;
        mx = fmaxf(mx, v[i]);
    }
    for (int d = 32; d; d >>= 1) mx = fmaxf(mx, __shfl_xor(mx, d));
    if ((tid & 63) == 0) red[tid >> 6] = mx;
    __syncthreads();
    if (tid == 0) {
        float m2 = red[0];
        for (int w = 1; w < 16; ++w) m2 = fmaxf(m2, red[w]);
        bc[0] = m2;
    }
    __syncthreads();
    mx = bc[0];
    float s = 0.f;
#pragma unroll
    for (int i = 0; i < 18; ++i) {
        int c = tid + (i << 10);
        if (c < VV) { v[i] = __expf(v[i] - mx); s += v[i]; }
    }
    for (int d = 32; d; d >>= 1) s += __shfl_xor(s, d);
    if ((tid & 63) == 0) red[tid >> 6] = s;
    __syncthreads();
    if (tid == 0) {
        float s2 = 0.f;
        for (int w = 0; w < 16; ++w) s2 += red[w];
        bc[1] = s2;
    }
    __syncthreads();
    float scale = swv / bc[1];
    float* orow = out + ((size_t)n * TDN + td) * VV;
#pragma unroll
    for (int i = 0; i < 18; ++i) {
        int c = tid + (i << 10);
        if (c < VV) orow[c] = v[i] * scale;
    }
    __syncthreads();
    if (tid < TE) {
        int b = n & 15;
        int tok = story[b * TE + tid];
        float val = (1.f - swv) * prow[tid];
        atomicAdd(orow + tok, val);
    }
}

static inline int cdiv(long long a, long long b) { return (int)((a + b - 1) / b); }

extern "C" void kernel_launch(void* const* d_in, const int* in_sizes, int n_in,
                              void* d_out, int out_size, void* d_ws, size_t ws_size,
                              hipStream_t stream) {
    const int*   story  = (const int*)d_in[0];
    const int*   target = (const int*)d_in[1];
    const float* emb    = (const float*)d_in[2];
    const float* wih_f  = (const float*)d_in[3];
    const float* whh_f  = (const float*)d_in[4];
    const float* bih_f  = (const float*)d_in[5];
    const float* bhh_f  = (const float*)d_in[6];
    const float* wih_b  = (const float*)d_in[7];
    const float* whh_b  = (const float*)d_in[8];
    const float* bih_b  = (const float*)d_in[9];
    const float* bhh_b  = (const float*)d_in[10];
    const float* dwih   = (const float*)d_in[11];
    const float* dwhh   = (const float*)d_in[12];
    const float* dbih   = (const float*)d_in[13];
    const float* dbhh   = (const float*)d_in[14];
    const float* wr     = (const float*)d_in[15];
    const float* brr    = (const float*)d_in[16];
    const float* wgg    = (const float*)d_in[17];
    const float* bgg    = (const float*)d_in[18];
    const float* slot   = (const float*)d_in[19];
    float* out = (float*)d_out;

    char* wsb = (char*)d_ws;
    size_t off = 0;
    auto alloc = [&](size_t bytes) -> char* {
        char* p = wsb + off;
        off = (off + bytes + 255) & ~(size_t)255;
        return p;
    };
    bf16*  embb  = (bf16*)alloc((size_t)VP * KP * 2);
    bf16*  aenc  = (bf16*)alloc((size_t)NROW_ENC * KP * 2);
    bf16*  wfb   = (bf16*)alloc((size_t)H3P * KP * 2);
    bf16*  wbb   = (bf16*)alloc((size_t)H3P * KP * 2);
    bf16*  dwihb = (bf16*)alloc((size_t)H3P * KP * 2);
    bf16*  dwhhb = (bf16*)alloc((size_t)H3P * KP * 2);
    bf16*  decxb = (bf16*)alloc((size_t)TDN * SBN * KP * 2);
    bf16*  h2ball= (bf16*)alloc((size_t)9 * MP_DEC * KP * 2);
    unsigned int* hbuff = (unsigned int*)alloc((size_t)TE * BB * KP * 4);
    unsigned int* hbufb = (unsigned int*)alloc((size_t)TE * BB * KP * 4);
    unsigned int* flags = (unsigned int*)alloc((size_t)(2 * TE * 32 + 2 * 32 * 16) * 4);
    unsigned int* gflags = flags + 2 * TE * 32;
    float* gif   = (float*)alloc((size_t)NROW_ENC * H3P * 4);
    float* gib   = (float*)alloc((size_t)NROW_ENC * H3P * 4);
    float* gidec = (float*)alloc((size_t)TDN * SBN * H3P * 4);
    float* ghdec = (float*)alloc((size_t)MP_DEC * H3P * 4);
    float* histf = (float*)alloc((size_t)TE * BB * HH * 4);
    float* histb = (float*)alloc((size_t)TE * BB * HH * 4);
    float* encout= (float*)alloc((size_t)BB * TE * HH * 4);
    float* decxf = (float*)alloc((size_t)TDN * SBN * HH * 4);
    float* hfall = (float*)alloc((size_t)9 * SBN * HH * 4);
    float* probw = (float*)alloc((size_t)TDN * SBN * TE * 4);
    float* sww   = (float*)alloc((size_t)TDN * SBN * 4);
    bf16*  logitsH = (bf16*)alloc((size_t)MP_DEC * VP * 2);
    const size_t bigBytes = (size_t)TDN * MP_DEC * VP * 2;
    bf16* logitsAllH = nullptr;
    if (off + bigBytes + 256 <= ws_size) logitsAllH = (bf16*)alloc(bigBytes);
    (void)in_sizes; (void)n_in; (void)out_size;

    (void)hipMemsetAsync(flags, 0, (size_t)(2 * TE * 32 + 2 * 32 * 16) * 4, stream);

    const int thr = 256;
    prep_all<<<1024, thr, 0, stream>>>(story, target, emb, slot, wih_f, wih_b, dwih, dwhh,
                                       aenc, wfb, wbb, dwihb, dwhhb, decxf, decxb, h2ball);

    // fat encoder: recurrence + (gi GEMMs with flags, gidec GEMM, embb prep)
    enc_fat<<<2 * EBLK + 2 * GI_TILES + GIDEC_TILES + EMBB_BLKS, 256, 0, stream>>>(
        gif, gib, whh_f, whh_b, bih_f, bhh_f, bih_b, bhh_b,
        histf, histb, hbuff, hbufb, flags, gflags,
        aenc, wfb, wbb, decxb, dwihb, gidec, emb, embb);

    combine_init<<<512, thr, 0, stream>>>(histf, histb, encout, hfall, h2ball);

    // phase 1: decoder h-chain
    for (int td = 0; td < TDN; ++td) {
        dim3 g(MP_DEC / 128, H3P / 128);
        gemm_bt<<<g, 256, 0, stream>>>(h2ball + (size_t)td * MP_DEC * KP, dwhhb, ghdec, nullptr,
                                       MP_DEC, H3P, KP, 0);
        gru_dec2<<<cdiv((long long)SBN * HH, thr), thr, 0, stream>>>(
            gidec + (size_t)td * SBN * H3P, ghdec, dbih, dbhh,
            hfall + (size_t)td * SBN * HH,
            hfall + (size_t)(td + 1) * SBN * HH,
            h2ball + (size_t)(td + 1) * MP_DEC * KP);
    }

    // phase 2: all attention in one launch
    {
        dim3 g(32, TDN);
        attn3<<<g, 256, 0, stream>>>(hfall, encout, decxf, wr, brr, wgg, bgg,
                                     probw, sww, out + (size_t)SBN * TDN * VV);
    }

    // phase 3: logits (bf16) + softmax/scatter
    if (logitsAllH) {
        dim3 g((TDN * MP_DEC) / 128, VP / 128);
        gemm_bt<<<g, 256, 0, stream>>>(h2ball + (size_t)MP_DEC * KP, embb, nullptr, logitsAllH,
                                       TDN * MP_DEC, VP, KP, 1);
        dim3 gs(SBN, TDN);
        smax_scatter3<<<gs, 1024, 0, stream>>>(logitsAllH, sww, story, probw, out, 0);
    } else {
        for (int td = 0; td < TDN; ++td) {
            dim3 g(MP_DEC / 128, VP / 128);
            gemm_bt<<<g, 256, 0, stream>>>(h2ball + (size_t)(td + 1) * MP_DEC * KP, embb,
                                           nullptr, logitsH, MP_DEC, VP, KP, 1);
            dim3 gs(SBN, 1);
            smax_scatter3<<<gs, 1024, 0, stream>>>(logitsH, sww, story, probw, out, td);
        }
    }
}

// Round 15
// 1711.763 us; speedup vs baseline: 1.1180x; 1.1180x over previous
//
#include <hip/hip_runtime.h>
#include <cstdint>
#include <cstddef>

#define VV 18000
#define HH 400
#define H3 1200
#define H3P 1280
#define KP 416
#define BB 16
#define TE 256
#define SS 30
#define TDN 8
#define GGN 3
#define SBN 480
#define NROW_ENC 4096
#define VP 18048
#define MP_DEC 512

#define EBLK 25          // enc blocks per direction
#define GIDEC_TILES 300  // (3840/128) x (1280/128)
#define EMBB_BLKS 256

typedef __bf16 bf16;
typedef __attribute__((ext_vector_type(8))) __bf16 bf16x8;
typedef __attribute__((ext_vector_type(4))) float f32x4;
typedef __attribute__((ext_vector_type(4))) unsigned int u32x4;

static __device__ __forceinline__ float sigf(float x) {
    return 1.0f / (1.0f + __expf(-x));
}

// ---------------- GEMM tile body (device fn): C = A(MxK) * B(NxK)^T, one 128x128 tile.
// Writes f32 to Cf or bf16 to Ch (exactly one non-null).
static __device__ void gemm_dev(const bf16* __restrict__ A, const bf16* __restrict__ B,
                                float* __restrict__ Cf, bf16* __restrict__ Ch,
                                int M, int N, int K, int m0, int n0) {
    __shared__ __align__(16) bf16 sA[128 * 32];
    __shared__ __align__(16) bf16 sB[128 * 32];
    const int tid = threadIdx.x;
    const int lane = tid & 63;
    const int wave = tid >> 6;
    const int wm = wave >> 1, wn = wave & 1;
    f32x4 acc[4][4] = {};
    const int c0 = tid, c1 = tid + 256;
    const int r0 = c0 >> 2, q0 = (c0 & 3) * 8;
    const int r1 = c1 >> 2, q1 = (c1 & 3) * 8;
    const int ar = lane & 15, ak = (lane >> 4) * 8;
    const int nk = K >> 5;
    for (int kt = 0; kt < nk; ++kt) {
        const int kb = kt * 32;
        uint4 a0 = *(const uint4*)(A + (size_t)(m0 + r0) * K + kb + q0);
        uint4 a1 = *(const uint4*)(A + (size_t)(m0 + r1) * K + kb + q1);
        uint4 b0 = *(const uint4*)(B + (size_t)(n0 + r0) * K + kb + q0);
        uint4 b1 = *(const uint4*)(B + (size_t)(n0 + r1) * K + kb + q1);
        __syncthreads();
        *(uint4*)(sA + r0 * 32 + q0) = a0;
        *(uint4*)(sA + r1 * 32 + q1) = a1;
        *(uint4*)(sB + r0 * 32 + q0) = b0;
        *(uint4*)(sB + r1 * 32 + q1) = b1;
        __syncthreads();
        bf16x8 af[4], bg[4];
#pragma unroll
        for (int i = 0; i < 4; ++i)
            af[i] = *(const bf16x8*)(sA + (wm * 64 + i * 16 + ar) * 32 + ak);
#pragma unroll
        for (int j = 0; j < 4; ++j)
            bg[j] = *(const bf16x8*)(sB + (wn * 64 + j * 16 + ar) * 32 + ak);
#pragma unroll
        for (int i = 0; i < 4; ++i)
#pragma unroll
            for (int j = 0; j < 4; ++j)
                acc[i][j] = __builtin_amdgcn_mfma_f32_16x16x32_bf16(af[i], bg[j], acc[i][j], 0, 0, 0);
    }
    const int cr = (lane >> 4) * 4, cc = lane & 15;
    if (Ch) {
#pragma unroll
        for (int i = 0; i < 4; ++i)
#pragma unroll
            for (int j = 0; j < 4; ++j)
#pragma unroll
                for (int q = 0; q < 4; ++q) {
                    int row = m0 + wm * 64 + i * 16 + cr + q;
                    int col = n0 + wn * 64 + j * 16 + cc;
                    Ch[(size_t)row * N + col] = (bf16)acc[i][j][q];
                }
    } else {
#pragma unroll
        for (int i = 0; i < 4; ++i)
#pragma unroll
            for (int j = 0; j < 4; ++j)
#pragma unroll
                for (int q = 0; q < 4; ++q) {
                    int row = m0 + wm * 64 + i * 16 + cr + q;
                    int col = n0 + wn * 64 + j * 16 + cc;
                    Cf[(size_t)row * N + col] = acc[i][j][q];
                }
    }
}

__global__ __launch_bounds__(256) void gemm_bt(const bf16* __restrict__ A,
                                               const bf16* __restrict__ B,
                                               float* __restrict__ Cf, bf16* __restrict__ Ch,
                                               int M, int N, int K) {
    gemm_dev(A, B, Cf, Ch, M, N, K, blockIdx.x * 128, blockIdx.y * 128);
}

// ---------------- prep kernels ----------------
__global__ void prep_pad_bf16(const float* __restrict__ src, bf16* __restrict__ dst,
                              int rows_real, int cols_real, int rows_pad, int cols_pad) {
    int idx = blockIdx.x * blockDim.x + threadIdx.x;
    int total = rows_pad * cols_pad;
    if (idx >= total) return;
    int r = idx / cols_pad, c = idx % cols_pad;
    float v = (r < rows_real && c < cols_real) ? src[(size_t)r * cols_real + c] : 0.f;
    dst[idx] = (bf16)v;
}

__global__ void prep_aenc(const int* __restrict__ story, const float* __restrict__ emb,
                          bf16* __restrict__ dst) {
    int idx = blockIdx.x * blockDim.x + threadIdx.x;
    if (idx >= NROW_ENC * KP) return;
    int m = idx / KP, k = idx % KP;
    int t = m >> 4, b = m & 15;
    float v = 0.f;
    if (k < HH) {
        int tok = story[b * TE + t];
        v = emb[(size_t)tok * HH + k];
    }
    dst[idx] = (bf16)v;
}

__global__ void prep_decx(const int* __restrict__ target, const float* __restrict__ emb,
                          const float* __restrict__ slot, float* __restrict__ xf,
                          bf16* __restrict__ xb) {
    int idx = blockIdx.x * blockDim.x + threadIdx.x;
    if (idx >= TDN * SBN * KP) return;
    int k = idx % KP;
    int nn = idx / KP;
    int n = nn % SBN;
    int td = nn / SBN;
    int s = n >> 4, b = n & 15;
    float v = 0.f;
    if (k < HH) {
        if (td == 0) v = slot[s * HH + k];
        else {
            int tok = target[(b * SS + s) * TDN + (td - 1)];
            v = emb[(size_t)tok * HH + k];
        }
        xf[((size_t)td * SBN + n) * HH + k] = v;
    }
    xb[idx] = (bf16)v;
}

__global__ void zero_bf16k(bf16* dst, size_t total) {
    size_t idx = (size_t)blockIdx.x * blockDim.x + threadIdx.x;
    if (idx < total) dst[idx] = (bf16)0.f;
}

// ---------------- fat encoder: blocks 0-49 recurrence; 50-349 gidec GEMM; 350+ embb prep --------
__global__ __launch_bounds__(256) void enc_fat(
    const float* __restrict__ gi_f, const float* __restrict__ gi_b,
    const float* __restrict__ whh_f, const float* __restrict__ whh_b,
    const float* __restrict__ bih_f, const float* __restrict__ bhh_f,
    const float* __restrict__ bih_b, const float* __restrict__ bhh_b,
    float* __restrict__ hist_f, float* __restrict__ hist_b,
    unsigned int* __restrict__ hbuf_f, unsigned int* __restrict__ hbuf_b,
    unsigned int* __restrict__ flags,
    const bf16* __restrict__ decxb, const bf16* __restrict__ dwihb,
    float* __restrict__ gidec,
    const float* __restrict__ emb, bf16* __restrict__ embb) {
    const int bid = blockIdx.x;
    const int tid = threadIdx.x;

    if (bid >= 2 * EBLK) {
        if (bid < 2 * EBLK + GIDEC_TILES) {
            // helper: one gidec tile (M=3840, N=1280, K=416)
            int t = bid - 2 * EBLK;
            gemm_dev(decxb, dwihb, gidec, nullptr, TDN * SBN, H3P, KP,
                     (t % 30) * 128, (t / 30) * 128);
        } else {
            // helper: embb prep, grid-stride
            const size_t total = (size_t)VP * KP;
            size_t idx = (size_t)(bid - 2 * EBLK - GIDEC_TILES) * 256 + tid;
            const size_t stride = (size_t)EMBB_BLKS * 256;
            for (; idx < total; idx += stride) {
                int r = (int)(idx / KP), c = (int)(idx % KP);
                float v = (r < VV && c < HH) ? emb[(size_t)r * HH + c] : 0.f;
                embb[idx] = (bf16)v;
            }
        }
        return;
    }

    // -------- encoder recurrence (identical to enc_rnn10) --------
    const int dir = bid & 1;
    const int blk = bid >> 1;
    const int j0 = blk * 16;
    const float* gi  = dir ? gi_b : gi_f;
    const float* whh = dir ? whh_b : whh_f;
    const float* bih = dir ? bih_b : bih_f;
    const float* bhh = dir ? bhh_b : bhh_f;
    float* hist = dir ? hist_b : hist_f;
    unsigned int* hbuf = dir ? hbuf_b : hbuf_f;

    __shared__ float GHL[3 * 256];

    const int wv = tid >> 6, lane = tid & 63;
    const int ub = tid >> 4, ucol = tid & 15;
    const int uj = j0 + ucol;
    const float bihr = bih[uj], bihz = bih[HH + uj], bihg = bih[2 * HH + uj];
    const float bhhr = bhh[uj], bhhz = bhh[HH + uj], bhhg = bhh[2 * HH + uj];

    const int kk0 = (lane >> 4) * 8;
    bf16x8 Bf[13];
    if (wv < 3) {
        const int brow = wv * HH + j0 + (lane & 15);
#pragma unroll
        for (int ks = 0; ks < 13; ++ks) {
            bf16x8 v;
#pragma unroll
            for (int e = 0; e < 8; ++e) {
                int k = kk0 + ks * 32 + e;
                v[e] = (k < HH) ? (bf16)whh[(size_t)brow * HH + k] : (bf16)0.f;
            }
            Bf[ks] = v;
        }
    }

    union UV { unsigned int d[4]; bf16x8 v; };

    float hp = 0.f;

    for (int s = 0; s < TE; ++s) {
        const int tt = dir ? (TE - 1 - s) : s;
        const float* gir = gi + ((size_t)tt * BB + ub) * H3P;
        float gi0 = gir[uj];
        float gi1 = gir[HH + uj];
        float gi2 = gir[2 * HH + uj];

        f32x4 acc0 = {}, acc1 = {};
        if (s > 0) {
            if (wv == 0) {
                const unsigned int* fl = flags + ((size_t)dir * TE + (s - 1)) * 32;
                while (true) {
                    unsigned f = 1u;
                    if (lane < EBLK)
                        asm volatile("global_load_dword %0, %1, off sc0 sc1"
                                     : "=v"(f) : "v"(fl + lane));
                    asm volatile("s_waitcnt vmcnt(0)" ::: "memory");
                    if (__all((int)(f != 0u))) break;
                }
            }
            __syncthreads();
            if (wv < 3) {
                const int ttp = dir ? (tt + 1) : (tt - 1);
                const unsigned int* hrow =
                    hbuf + ((size_t)ttp * BB + (lane & 15)) * KP + kk0;
                u32x4 ua[13], ubv[13];
#pragma unroll
                for (int ks = 0; ks < 13; ++ks) {
                    asm volatile("global_load_dwordx4 %0, %1, off offset:%c2 sc0 sc1"
                                 : "=v"(ua[ks]) : "v"(hrow), "n"(ks * 128));
                    asm volatile("global_load_dwordx4 %0, %1, off offset:%c2 sc0 sc1"
                                 : "=v"(ubv[ks]) : "v"(hrow), "n"(ks * 128 + 16));
                }
                asm volatile("s_waitcnt vmcnt(0)" ::: "memory");
                __builtin_amdgcn_sched_barrier(0);
#pragma unroll
                for (int ks = 0; ks < 13; ++ks) {
                    u32x4 a = ua[ks], b = ubv[ks];
                    UV ah, al;
                    ah.d[0] = (a.x & 0xffffu) | (a.y << 16);
                    ah.d[1] = (a.z & 0xffffu) | (a.w << 16);
                    ah.d[2] = (b.x & 0xffffu) | (b.y << 16);
                    ah.d[3] = (b.z & 0xffffu) | (b.w << 16);
                    al.d[0] = (a.x >> 16) | (a.y & 0xffff0000u);
                    al.d[1] = (a.z >> 16) | (a.w & 0xffff0000u);
                    al.d[2] = (b.x >> 16) | (b.y & 0xffff0000u);
                    al.d[3] = (b.z >> 16) | (b.w & 0xffff0000u);
                    acc0 = __builtin_amdgcn_mfma_f32_16x16x32_bf16(ah.v, Bf[ks], acc0, 0, 0, 0);
                    acc1 = __builtin_amdgcn_mfma_f32_16x16x32_bf16(al.v, Bf[ks], acc1, 0, 0, 0);
                }
            }
        }
        if (wv < 3) {
            f32x4 at = acc0 + acc1;
            const int cb0 = wv * 256 + ((lane >> 4) * 4) * 16 + (lane & 15);
            GHL[cb0]      = at[0];
            GHL[cb0 + 16] = at[1];
            GHL[cb0 + 32] = at[2];
            GHL[cb0 + 48] = at[3];
        }
        __syncthreads();

        float ghr = GHL[tid];
        float ghz = GHL[256 + tid];
        float ghg = GHL[512 + tid];
        float r = sigf(gi0 + bihr + ghr + bhhr);
        float z = sigf(gi1 + bihz + ghz + bhhz);
        float g = tanhf(gi2 + bihg + r * (ghg + bhhg));
        float hn = (1.f - z) * g + z * hp;
        hp = hn;
        hist[((size_t)tt * BB + ub) * HH + uj] = hn;
        bf16 hi = (bf16)hn;
        bf16 lo = (bf16)(hn - (float)hi);
        unsigned int pk = (unsigned int)__builtin_bit_cast(unsigned short, hi)
                        | ((unsigned int)__builtin_bit_cast(unsigned short, lo) << 16);
        unsigned int* hw = hbuf + ((size_t)tt * BB + ub) * KP + uj;
        asm volatile("global_store_dword %0, %1, off sc0 sc1" :: "v"(hw), "v"(pk) : "memory");

        asm volatile("s_waitcnt vmcnt(0)" ::: "memory");
        __syncthreads();
        if (tid == 0) {
            unsigned int one = 1u;
            unsigned int* fw = flags + ((size_t)dir * TE + s) * 32 + blk;
            asm volatile("global_store_dword %0, %1, off sc0 sc1" :: "v"(fw), "v"(one) : "memory");
        }
    }
}

__global__ void combine_enc(const float* __restrict__ hf, const float* __restrict__ hb,
                            float* __restrict__ enc_out) {
    int idx = blockIdx.x * blockDim.x + threadIdx.x;
    if (idx >= BB * TE * HH) return;
    int hcol = idx % HH;
    int t = (idx / HH) % TE;
    int b = idx / (HH * TE);
    size_t src = ((size_t)t * BB + b) * HH + hcol;
    enc_out[idx] = hf[src] + hb[src];
}

__global__ void init_hdec2(const float* __restrict__ hf, const float* __restrict__ hb,
                           float* __restrict__ hdec, bf16* __restrict__ h2b) {
    int idx = blockIdx.x * blockDim.x + threadIdx.x;
    if (idx >= SBN * HH) return;
    int hcol = idx % HH;
    int n = idx / HH;
    int b = n & 15;
    float v = hf[((size_t)(TE - 1) * BB + b) * HH + hcol] + hb[((size_t)b) * HH + hcol];
    hdec[idx] = v;
    h2b[(size_t)n * KP + hcol] = (bf16)v;
}

__global__ void gru_dec2(const float* __restrict__ gi, const float* __restrict__ gh,
                         const float* __restrict__ bih, const float* __restrict__ bhh,
                         const float* __restrict__ hprev, float* __restrict__ hnew,
                         bf16* __restrict__ h2b) {
    int idx = blockIdx.x * blockDim.x + threadIdx.x;
    if (idx >= SBN * HH) return;
    int n = idx / HH, j = idx % HH;
    const float* gir = gi + (size_t)n * H3P;
    const float* ghr = gh + (size_t)n * H3P;
    float r = sigf(gir[j] + bih[j] + ghr[j] + bhh[j]);
    float z = sigf(gir[HH + j] + bih[HH + j] + ghr[HH + j] + bhh[HH + j]);
    float g = tanhf(gir[2 * HH + j] + bih[2 * HH + j] + r * (ghr[2 * HH + j] + bhh[2 * HH + j]));
    float hn = (1.f - z) * g + z * hprev[idx];
    hnew[idx] = hn;
    h2b[(size_t)n * KP + j] = (bf16)hn;
}

// ---------------- bulk attention ----------------
__global__ __launch_bounds__(256) void attn3(
    const float* __restrict__ hfall,
    const float* __restrict__ enc,
    const float* __restrict__ decxf,
    const float* __restrict__ Wr, const float* __restrict__ br,
    const float* __restrict__ Wg, const float* __restrict__ bg,
    float* __restrict__ probw,
    float* __restrict__ sww,
    float* __restrict__ outg) {
    const int b = blockIdx.x >> 1;
    const int half = blockIdx.x & 1;
    const int td = blockIdx.y;
    const int s0 = half * 15;
    const int tid = threadIdx.x;
    const int lane = tid & 63, wv = tid >> 6;

    __shared__ __align__(16) float h2L[15][HH];
    __shared__ __align__(16) float scL[15][TE];
    __shared__ __align__(16) float cxL[15][HH];

    const float* h2base = hfall + (size_t)(td + 1) * SBN * HH;
    for (int i = tid; i < 15 * HH; i += 256) {
        int j = i / HH, k = i % HH;
        int n = (s0 + j) * BB + b;
        h2L[j][k] = h2base[(size_t)n * HH + k];
    }
    __syncthreads();

    {
        float acc[15];
#pragma unroll
        for (int j = 0; j < 15; ++j) acc[j] = 0.f;
        const float4* er = (const float4*)(enc + ((size_t)b * TE + tid) * HH);
        for (int k4 = 0; k4 < HH / 4; ++k4) {
            float4 e = er[k4];
#pragma unroll
            for (int j = 0; j < 15; ++j) {
                float4 hv = *(const float4*)(&h2L[j][k4 * 4]);
                acc[j] += e.x * hv.x + e.y * hv.y + e.z * hv.z + e.w * hv.w;
            }
        }
#pragma unroll
        for (int j = 0; j < 15; ++j) scL[j][tid] = acc[j];
    }
    __syncthreads();

    for (int j = wv; j < 15; j += 4) {
        float v0 = scL[j][lane], v1 = scL[j][lane + 64];
        float v2 = scL[j][lane + 128], v3 = scL[j][lane + 192];
        float m = fmaxf(fmaxf(v0, v1), fmaxf(v2, v3));
        for (int d = 32; d; d >>= 1) m = fmaxf(m, __shfl_xor(m, d));
        v0 = __expf(v0 - m); v1 = __expf(v1 - m);
        v2 = __expf(v2 - m); v3 = __expf(v3 - m);
        float s = v0 + v1 + v2 + v3;
        for (int d = 32; d; d >>= 1) s += __shfl_xor(s, d);
        float inv = 1.f / s;
        scL[j][lane]       = v0 * inv;
        scL[j][lane + 64]  = v1 * inv;
        scL[j][lane + 128] = v2 * inv;
        scL[j][lane + 192] = v3 * inv;
    }
    __syncthreads();

    for (int i = tid; i < 15 * TE; i += 256) {
        int j = i / TE, t = i % TE;
        int n = (s0 + j) * BB + b;
        probw[((size_t)td * SBN + n) * TE + t] = scL[j][t];
    }

    {
        float cx0[15], cx1[15];
#pragma unroll
        for (int j = 0; j < 15; ++j) { cx0[j] = 0.f; cx1[j] = 0.f; }
        const int c0 = tid, c1 = tid + 256;
        const bool has2 = (c1 < HH);
        for (int t = 0; t < TE; t += 2) {
            const float* e0r = enc + ((size_t)b * TE + t) * HH;
            const float* e1r = e0r + HH;
            float e00 = e0r[c0], e01 = e1r[c0];
            float e10 = 0.f, e11 = 0.f;
            if (has2) { e10 = e0r[c1]; e11 = e1r[c1]; }
#pragma unroll
            for (int j = 0; j < 15; ++j) {
                float2 p = *(const float2*)(&scL[j][t]);
                cx0[j] += p.x * e00 + p.y * e01;
                cx1[j] += p.x * e10 + p.y * e11;
            }
        }
#pragma unroll
        for (int j = 0; j < 15; ++j) {
            cxL[j][c0] = cx0[j];
            if (has2) cxL[j][c1] = cx1[j];
        }
    }
    __syncthreads();

    for (int j = wv; j < 15; j += 4) {
        int n = (s0 + j) * BB + b;
        const float* dx = decxf + ((size_t)td * SBN + n) * HH;
        float a = 0.f;
        for (int k = lane; k < H3; k += 64) {
            float v = (k < HH) ? h2L[j][k]
                    : (k < 2 * HH) ? cxL[j][k - HH]
                    : dx[k - 2 * HH];
            a += v * Wr[k];
        }
        for (int d = 32; d; d >>= 1) a += __shfl_xor(a, d);
        if (lane == 0) sww[(size_t)td * SBN + n] = sigf(a + br[0]);
    }

    if (td == 0) {
        for (int j = wv; j < 15; j += 4) {
            int n = (s0 + j) * BB + b;
#pragma unroll
            for (int g = 0; g < GGN; ++g) {
                float a = 0.f;
                for (int k = lane; k < HH; k += 64) a += cxL[j][k] * Wg[g * HH + k];
                for (int d = 32; d; d >>= 1) a += __shfl_xor(a, d);
                if (lane == 0) outg[n * GGN + g] = a + bg[g];
            }
        }
    }
}

// softmax over vocab (bf16 logits) + final write + fused pointer scatter.
__global__ __launch_bounds__(1024) void smax_scatter3(
    const bf16* __restrict__ logitsH, const float* __restrict__ sw,
    const int* __restrict__ story, const float* __restrict__ probw,
    float* __restrict__ out, int td0) {
    int n = blockIdx.x, tid = threadIdx.x;
    int td = td0 + blockIdx.y;
    const bf16* lrow = logitsH + ((size_t)blockIdx.y * MP_DEC + n) * VP;
    const float* prow = probw + ((size_t)td * SBN + n) * TE;
    float swv = sw[(size_t)td * SBN + n];
    __shared__ float red[16];
    __shared__ float bc[2];
    float v[18];
    float mx = -1e30f;
#pragma unroll
    for (int i = 0; i < 18; ++i) {
        int c = tid + (i << 10);
        v[i] = (c < VV) ? (float)lrow[c] : -1e30f;
        mx = fmaxf(mx, v[i]);
    }
    for (int d = 32; d; d >>= 1) mx = fmaxf(mx, __shfl_xor(mx, d));
    if ((tid & 63) == 0) red[tid >> 6] = mx;
    __syncthreads();
    if (tid == 0) {
        float m2 = red[0];
        for (int w = 1; w < 16; ++w) m2 = fmaxf(m2, red[w]);
        bc[0] = m2;
    }
    __syncthreads();
    mx = bc[0];
    float s = 0.f;
#pragma unroll
    for (int i = 0; i < 18; ++i) {
        int c = tid + (i << 10);
        if (c < VV) { v[i] = __expf(v[i] - mx); s += v[i]; }
    }
    for (int d = 32; d; d >>= 1) s += __shfl_xor(s, d);
    if ((tid & 63) == 0) red[tid >> 6] = s;
    __syncthreads();
    if (tid == 0) {
        float s2 = 0.f;
        for (int w = 0; w < 16; ++w) s2 += red[w];
        bc[1] = s2;
    }
    __syncthreads();
    float scale = swv / bc[1];
    float* orow = out + ((size_t)n * TDN + td) * VV;
#pragma unroll
    for (int i = 0; i < 18; ++i) {
        int c = tid + (i << 10);
        if (c < VV) orow[c] = v[i] * scale;
    }
    __syncthreads();
    if (tid < TE) {
        int b = n & 15;
        int tok = story[b * TE + tid];
        float val = (1.f - swv) * prow[tid];
        atomicAdd(orow + tok, val);
    }
}

static inline int cdiv(long long a, long long b) { return (int)((a + b - 1) / b); }

extern "C" void kernel_launch(void* const* d_in, const int* in_sizes, int n_in,
                              void* d_out, int out_size, void* d_ws, size_t ws_size,
                              hipStream_t stream) {
    const int*   story  = (const int*)d_in[0];
    const int*   target = (const int*)d_in[1];
    const float* emb    = (const float*)d_in[2];
    const float* wih_f  = (const float*)d_in[3];
    const float* whh_f  = (const float*)d_in[4];
    const float* bih_f  = (const float*)d_in[5];
    const float* bhh_f  = (const float*)d_in[6];
    const float* wih_b  = (const float*)d_in[7];
    const float* whh_b  = (const float*)d_in[8];
    const float* bih_b  = (const float*)d_in[9];
    const float* bhh_b  = (const float*)d_in[10];
    const float* dwih   = (const float*)d_in[11];
    const float* dwhh   = (const float*)d_in[12];
    const float* dbih   = (const float*)d_in[13];
    const float* dbhh   = (const float*)d_in[14];
    const float* wr     = (const float*)d_in[15];
    const float* brr    = (const float*)d_in[16];
    const float* wgg    = (const float*)d_in[17];
    const float* bgg    = (const float*)d_in[18];
    const float* slot   = (const float*)d_in[19];
    float* out = (float*)d_out;

    char* wsb = (char*)d_ws;
    size_t off = 0;
    auto alloc = [&](size_t bytes) -> char* {
        char* p = wsb + off;
        off = (off + bytes + 255) & ~(size_t)255;
        return p;
    };
    bf16*  embb  = (bf16*)alloc((size_t)VP * KP * 2);
    bf16*  aenc  = (bf16*)alloc((size_t)NROW_ENC * KP * 2);
    bf16*  wfb   = (bf16*)alloc((size_t)H3P * KP * 2);
    bf16*  wbb   = (bf16*)alloc((size_t)H3P * KP * 2);
    bf16*  dwihb = (bf16*)alloc((size_t)H3P * KP * 2);
    bf16*  dwhhb = (bf16*)alloc((size_t)H3P * KP * 2);
    bf16*  decxb = (bf16*)alloc((size_t)TDN * SBN * KP * 2);
    bf16*  h2ball= (bf16*)alloc((size_t)9 * MP_DEC * KP * 2);
    unsigned int* hbuff = (unsigned int*)alloc((size_t)TE * BB * KP * 4);
    unsigned int* hbufb = (unsigned int*)alloc((size_t)TE * BB * KP * 4);
    unsigned int* flags = (unsigned int*)alloc((size_t)2 * TE * 32 * 4);
    float* gif   = (float*)alloc((size_t)NROW_ENC * H3P * 4);
    float* gib   = (float*)alloc((size_t)NROW_ENC * H3P * 4);
    float* gidec = (float*)alloc((size_t)TDN * SBN * H3P * 4);
    float* ghdec = (float*)alloc((size_t)MP_DEC * H3P * 4);
    float* histf = (float*)alloc((size_t)TE * BB * HH * 4);
    float* histb = (float*)alloc((size_t)TE * BB * HH * 4);
    float* encout= (float*)alloc((size_t)BB * TE * HH * 4);
    float* decxf = (float*)alloc((size_t)TDN * SBN * HH * 4);
    float* hfall = (float*)alloc((size_t)9 * SBN * HH * 4);
    float* probw = (float*)alloc((size_t)TDN * SBN * TE * 4);
    float* sww   = (float*)alloc((size_t)TDN * SBN * 4);
    bf16*  logitsH = (bf16*)alloc((size_t)MP_DEC * VP * 2);
    // batched bf16 logits buffer (148 MB) only if workspace allows
    const size_t bigBytes = (size_t)TDN * MP_DEC * VP * 2;
    bf16* logitsAllH = nullptr;
    if (off + bigBytes + 256 <= ws_size) logitsAllH = (bf16*)alloc(bigBytes);
    (void)in_sizes; (void)n_in; (void)out_size;

    (void)hipMemsetAsync(flags, 0, (size_t)2 * TE * 32 * 4, stream);

    const int thr = 256;
    prep_aenc<<<cdiv((long long)NROW_ENC * KP, thr), thr, 0, stream>>>(story, emb, aenc);
    prep_pad_bf16<<<cdiv((long long)H3P * KP, thr), thr, 0, stream>>>(wih_f, wfb, H3, HH, H3P, KP);
    prep_pad_bf16<<<cdiv((long long)H3P * KP, thr), thr, 0, stream>>>(wih_b, wbb, H3, HH, H3P, KP);
    prep_pad_bf16<<<cdiv((long long)H3P * KP, thr), thr, 0, stream>>>(dwih, dwihb, H3, HH, H3P, KP);
    prep_pad_bf16<<<cdiv((long long)H3P * KP, thr), thr, 0, stream>>>(dwhh, dwhhb, H3, HH, H3P, KP);
    prep_decx<<<cdiv((long long)TDN * SBN * KP, thr), thr, 0, stream>>>(target, emb, slot, decxf, decxb);
    zero_bf16k<<<cdiv((long long)9 * MP_DEC * KP, thr), thr, 0, stream>>>(h2ball, (size_t)9 * MP_DEC * KP);

    {
        dim3 g(NROW_ENC / 128, H3P / 128);
        gemm_bt<<<g, 256, 0, stream>>>(aenc, wfb, gif, nullptr, NROW_ENC, H3P, KP);
        gemm_bt<<<g, 256, 0, stream>>>(aenc, wbb, gib, nullptr, NROW_ENC, H3P, KP);
    }

    // fat encoder: recurrence + (gidec GEMM, embb prep) on idle CUs
    enc_fat<<<2 * EBLK + GIDEC_TILES + EMBB_BLKS, 256, 0, stream>>>(
        gif, gib, whh_f, whh_b, bih_f, bhh_f, bih_b, bhh_b,
        histf, histb, hbuff, hbufb, flags,
        decxb, dwihb, gidec, emb, embb);

    combine_enc<<<cdiv((long long)BB * TE * HH, thr), thr, 0, stream>>>(histf, histb, encout);
    init_hdec2<<<cdiv((long long)SBN * HH, thr), thr, 0, stream>>>(histf, histb, hfall, h2ball);

    // phase 1: decoder h-chain
    for (int td = 0; td < TDN; ++td) {
        dim3 g(MP_DEC / 128, H3P / 128);
        gemm_bt<<<g, 256, 0, stream>>>(h2ball + (size_t)td * MP_DEC * KP, dwhhb, ghdec, nullptr,
                                       MP_DEC, H3P, KP);
        gru_dec2<<<cdiv((long long)SBN * HH, thr), thr, 0, stream>>>(
            gidec + (size_t)td * SBN * H3P, ghdec, dbih, dbhh,
            hfall + (size_t)td * SBN * HH,
            hfall + (size_t)(td + 1) * SBN * HH,
            h2ball + (size_t)(td + 1) * MP_DEC * KP);
    }

    // phase 2: all attention in one launch
    {
        dim3 g(32, TDN);
        attn3<<<g, 256, 0, stream>>>(hfall, encout, decxf, wr, brr, wgg, bgg,
                                     probw, sww, out + (size_t)SBN * TDN * VV);
    }

    // phase 3: logits (bf16) + softmax/scatter
    if (logitsAllH) {
        dim3 g((TDN * MP_DEC) / 128, VP / 128);
        gemm_bt<<<g, 256, 0, stream>>>(h2ball + (size_t)MP_DEC * KP, embb, nullptr, logitsAllH,
                                       TDN * MP_DEC, VP, KP);
        dim3 gs(SBN, TDN);
        smax_scatter3<<<gs, 1024, 0, stream>>>(logitsAllH, sww, story, probw, out, 0);
    } else {
        for (int td = 0; td < TDN; ++td) {
            dim3 g(MP_DEC / 128, VP / 128);
            gemm_bt<<<g, 256, 0, stream>>>(h2ball + (size_t)(td + 1) * MP_DEC * KP, embb,
                                           nullptr, logitsH, MP_DEC, VP, KP);
            dim3 gs(SBN, 1);
            smax_scatter3<<<gs, 1024, 0, stream>>>(logitsH, sww, story, probw, out, td);
        }
    }
}

// Round 17
// 1704.959 us; speedup vs baseline: 1.1224x; 1.0040x over previous
//
#include <hip/hip_runtime.h>
#include <cstdint>
#include <cstddef>

#define VV 18000
#define HH 400
#define H3 1200
#define H3P 1280
#define KP 416
#define BB 16
#define TE 256
#define SS 30
#define TDN 8
#define GGN 3
#define SBN 480
#define NROW_ENC 4096
#define VP 18048
#define MP_DEC 512

#define EBLK 25          // enc blocks per direction
#define GIDEC_TILES 300  // (3840/128) x (1280/128)
#define EMBB_BLKS 256

typedef __bf16 bf16;
typedef __attribute__((ext_vector_type(8))) __bf16 bf16x8;
typedef __attribute__((ext_vector_type(4))) float f32x4;
typedef __attribute__((ext_vector_type(4))) unsigned int u32x4;

static __device__ __forceinline__ float sigf(float x) {
    return 1.0f / (1.0f + __expf(-x));
}

// ---------------- GEMM tile body (device fn): C = A(MxK) * B(NxK)^T, one 128x128 tile.
static __device__ void gemm_dev(const bf16* __restrict__ A, const bf16* __restrict__ B,
                                float* __restrict__ Cf, bf16* __restrict__ Ch,
                                int M, int N, int K, int m0, int n0) {
    __shared__ __align__(16) bf16 sA[128 * 32];
    __shared__ __align__(16) bf16 sB[128 * 32];
    const int tid = threadIdx.x;
    const int lane = tid & 63;
    const int wave = tid >> 6;
    const int wm = wave >> 1, wn = wave & 1;
    f32x4 acc[4][4] = {};
    const int c0 = tid, c1 = tid + 256;
    const int r0 = c0 >> 2, q0 = (c0 & 3) * 8;
    const int r1 = c1 >> 2, q1 = (c1 & 3) * 8;
    const int ar = lane & 15, ak = (lane >> 4) * 8;
    const int nk = K >> 5;
    for (int kt = 0; kt < nk; ++kt) {
        const int kb = kt * 32;
        uint4 a0 = *(const uint4*)(A + (size_t)(m0 + r0) * K + kb + q0);
        uint4 a1 = *(const uint4*)(A + (size_t)(m0 + r1) * K + kb + q1);
        uint4 b0 = *(const uint4*)(B + (size_t)(n0 + r0) * K + kb + q0);
        uint4 b1 = *(const uint4*)(B + (size_t)(n0 + r1) * K + kb + q1);
        __syncthreads();
        *(uint4*)(sA + r0 * 32 + q0) = a0;
        *(uint4*)(sA + r1 * 32 + q1) = a1;
        *(uint4*)(sB + r0 * 32 + q0) = b0;
        *(uint4*)(sB + r1 * 32 + q1) = b1;
        __syncthreads();
        bf16x8 af[4], bg[4];
#pragma unroll
        for (int i = 0; i < 4; ++i)
            af[i] = *(const bf16x8*)(sA + (wm * 64 + i * 16 + ar) * 32 + ak);
#pragma unroll
        for (int j = 0; j < 4; ++j)
            bg[j] = *(const bf16x8*)(sB + (wn * 64 + j * 16 + ar) * 32 + ak);
#pragma unroll
        for (int i = 0; i < 4; ++i)
#pragma unroll
            for (int j = 0; j < 4; ++j)
                acc[i][j] = __builtin_amdgcn_mfma_f32_16x16x32_bf16(af[i], bg[j], acc[i][j], 0, 0, 0);
    }
    const int cr = (lane >> 4) * 4, cc = lane & 15;
    if (Ch) {
#pragma unroll
        for (int i = 0; i < 4; ++i)
#pragma unroll
            for (int j = 0; j < 4; ++j)
#pragma unroll
                for (int q = 0; q < 4; ++q) {
                    int row = m0 + wm * 64 + i * 16 + cr + q;
                    int col = n0 + wn * 64 + j * 16 + cc;
                    Ch[(size_t)row * N + col] = (bf16)acc[i][j][q];
                }
    } else {
#pragma unroll
        for (int i = 0; i < 4; ++i)
#pragma unroll
            for (int j = 0; j < 4; ++j)
#pragma unroll
                for (int q = 0; q < 4; ++q) {
                    int row = m0 + wm * 64 + i * 16 + cr + q;
                    int col = n0 + wn * 64 + j * 16 + cc;
                    Cf[(size_t)row * N + col] = acc[i][j][q];
                }
    }
}

__global__ __launch_bounds__(256) void gemm_bt(const bf16* __restrict__ A,
                                               const bf16* __restrict__ B,
                                               float* __restrict__ Cf, bf16* __restrict__ Ch,
                                               int M, int N, int K) {
    gemm_dev(A, B, Cf, Ch, M, N, K, blockIdx.x * 128, blockIdx.y * 128);
}

// both gi GEMMs in one launch (z = dir)
__global__ __launch_bounds__(256) void gemm_gi(const bf16* __restrict__ aenc,
                                               const bf16* __restrict__ wfb,
                                               const bf16* __restrict__ wbb,
                                               float* __restrict__ gif, float* __restrict__ gib) {
    const int dir = blockIdx.z;
    gemm_dev(aenc, dir ? wbb : wfb, dir ? gib : gif, nullptr,
             NROW_ENC, H3P, KP, blockIdx.x * 128, blockIdx.y * 128);
}

// ---------------- prep kernels ----------------
__global__ void prep_wpad4(const float* __restrict__ wih_f, const float* __restrict__ wih_b,
                           const float* __restrict__ dwih, const float* __restrict__ dwhh,
                           bf16* __restrict__ wfb, bf16* __restrict__ wbb,
                           bf16* __restrict__ dwihb, bf16* __restrict__ dwhhb) {
    int idx = blockIdx.x * blockDim.x + threadIdx.x;
    if (idx >= H3P * KP) return;
    int r = idx / KP, c = idx % KP;
    bool in = (r < H3 && c < HH);
    const float* src;
    bf16* dst;
    switch (blockIdx.y) {
        case 0: src = wih_f; dst = wfb; break;
        case 1: src = wih_b; dst = wbb; break;
        case 2: src = dwih; dst = dwihb; break;
        default: src = dwhh; dst = dwhhb; break;
    }
    dst[idx] = (bf16)(in ? src[(size_t)r * HH + c] : 0.f);
}

__global__ void prep_aenc(const int* __restrict__ story, const float* __restrict__ emb,
                          bf16* __restrict__ dst) {
    int idx = blockIdx.x * blockDim.x + threadIdx.x;
    if (idx >= NROW_ENC * KP) return;
    int m = idx / KP, k = idx % KP;
    int t = m >> 4, b = m & 15;
    float v = 0.f;
    if (k < HH) {
        int tok = story[b * TE + t];
        v = emb[(size_t)tok * HH + k];
    }
    dst[idx] = (bf16)v;
}

__global__ void prep_decx(const int* __restrict__ target, const float* __restrict__ emb,
                          const float* __restrict__ slot, float* __restrict__ xf,
                          bf16* __restrict__ xb) {
    int idx = blockIdx.x * blockDim.x + threadIdx.x;
    if (idx >= TDN * SBN * KP) return;
    int k = idx % KP;
    int nn = idx / KP;
    int n = nn % SBN;
    int td = nn / SBN;
    int s = n >> 4, b = n & 15;
    float v = 0.f;
    if (k < HH) {
        if (td == 0) v = slot[s * HH + k];
        else {
            int tok = target[(b * SS + s) * TDN + (td - 1)];
            v = emb[(size_t)tok * HH + k];
        }
        xf[((size_t)td * SBN + n) * HH + k] = v;
    }
    xb[idx] = (bf16)v;
}

__global__ void zero_bf16k(bf16* dst, size_t total) {
    size_t idx = (size_t)blockIdx.x * blockDim.x + threadIdx.x;
    if (idx < total) dst[idx] = (bf16)0.f;
}

// ---------------- fat encoder (unchanged from R13/R15) --------
__global__ __launch_bounds__(256) void enc_fat(
    const float* __restrict__ gi_f, const float* __restrict__ gi_b,
    const float* __restrict__ whh_f, const float* __restrict__ whh_b,
    const float* __restrict__ bih_f, const float* __restrict__ bhh_f,
    const float* __restrict__ bih_b, const float* __restrict__ bhh_b,
    float* __restrict__ hist_f, float* __restrict__ hist_b,
    unsigned int* __restrict__ hbuf_f, unsigned int* __restrict__ hbuf_b,
    unsigned int* __restrict__ flags,
    const bf16* __restrict__ decxb, const bf16* __restrict__ dwihb,
    float* __restrict__ gidec,
    const float* __restrict__ emb, bf16* __restrict__ embb) {
    const int bid = blockIdx.x;
    const int tid = threadIdx.x;

    if (bid >= 2 * EBLK) {
        if (bid < 2 * EBLK + GIDEC_TILES) {
            int t = bid - 2 * EBLK;
            gemm_dev(decxb, dwihb, gidec, nullptr, TDN * SBN, H3P, KP,
                     (t % 30) * 128, (t / 30) * 128);
        } else {
            const size_t total = (size_t)VP * KP;
            size_t idx = (size_t)(bid - 2 * EBLK - GIDEC_TILES) * 256 + tid;
            const size_t stride = (size_t)EMBB_BLKS * 256;
            for (; idx < total; idx += stride) {
                int r = (int)(idx / KP), c = (int)(idx % KP);
                float v = (r < VV && c < HH) ? emb[(size_t)r * HH + c] : 0.f;
                embb[idx] = (bf16)v;
            }
        }
        return;
    }

    const int dir = bid & 1;
    const int blk = bid >> 1;
    const int j0 = blk * 16;
    const float* gi  = dir ? gi_b : gi_f;
    const float* whh = dir ? whh_b : whh_f;
    const float* bih = dir ? bih_b : bih_f;
    const float* bhh = dir ? bhh_b : bhh_f;
    float* hist = dir ? hist_b : hist_f;
    unsigned int* hbuf = dir ? hbuf_b : hbuf_f;

    __shared__ float GHL[3 * 256];

    const int wv = tid >> 6, lane = tid & 63;
    const int ub = tid >> 4, ucol = tid & 15;
    const int uj = j0 + ucol;
    const float bihr = bih[uj], bihz = bih[HH + uj], bihg = bih[2 * HH + uj];
    const float bhhr = bhh[uj], bhhz = bhh[HH + uj], bhhg = bhh[2 * HH + uj];

    const int kk0 = (lane >> 4) * 8;
    bf16x8 Bf[13];
    if (wv < 3) {
        const int brow = wv * HH + j0 + (lane & 15);
#pragma unroll
        for (int ks = 0; ks < 13; ++ks) {
            bf16x8 v;
#pragma unroll
            for (int e = 0; e < 8; ++e) {
                int k = kk0 + ks * 32 + e;
                v[e] = (k < HH) ? (bf16)whh[(size_t)brow * HH + k] : (bf16)0.f;
            }
            Bf[ks] = v;
        }
    }

    union UV { unsigned int d[4]; bf16x8 v; };

    float hp = 0.f;

    for (int s = 0; s < TE; ++s) {
        const int tt = dir ? (TE - 1 - s) : s;
        const float* gir = gi + ((size_t)tt * BB + ub) * H3P;
        float gi0 = gir[uj];
        float gi1 = gir[HH + uj];
        float gi2 = gir[2 * HH + uj];

        f32x4 acc0 = {}, acc1 = {};
        if (s > 0) {
            if (wv == 0) {
                const unsigned int* fl = flags + ((size_t)dir * TE + (s - 1)) * 32;
                while (true) {
                    unsigned f = 1u;
                    if (lane < EBLK)
                        asm volatile("global_load_dword %0, %1, off sc0 sc1"
                                     : "=v"(f) : "v"(fl + lane));
                    asm volatile("s_waitcnt vmcnt(0)" ::: "memory");
                    if (__all((int)(f != 0u))) break;
                }
            }
            __syncthreads();
            if (wv < 3) {
                const int ttp = dir ? (tt + 1) : (tt - 1);
                const unsigned int* hrow =
                    hbuf + ((size_t)ttp * BB + (lane & 15)) * KP + kk0;
                u32x4 ua[13], ubv[13];
#pragma unroll
                for (int ks = 0; ks < 13; ++ks) {
                    asm volatile("global_load_dwordx4 %0, %1, off offset:%c2 sc0 sc1"
                                 : "=v"(ua[ks]) : "v"(hrow), "n"(ks * 128));
                    asm volatile("global_load_dwordx4 %0, %1, off offset:%c2 sc0 sc1"
                                 : "=v"(ubv[ks]) : "v"(hrow), "n"(ks * 128 + 16));
                }
                asm volatile("s_waitcnt vmcnt(0)" ::: "memory");
                __builtin_amdgcn_sched_barrier(0);
#pragma unroll
                for (int ks = 0; ks < 13; ++ks) {
                    u32x4 a = ua[ks], b = ubv[ks];
                    UV ah, al;
                    ah.d[0] = (a.x & 0xffffu) | (a.y << 16);
                    ah.d[1] = (a.z & 0xffffu) | (a.w << 16);
                    ah.d[2] = (b.x & 0xffffu) | (b.y << 16);
                    ah.d[3] = (b.z & 0xffffu) | (b.w << 16);
                    al.d[0] = (a.x >> 16) | (a.y & 0xffff0000u);
                    al.d[1] = (a.z >> 16) | (a.w & 0xffff0000u);
                    al.d[2] = (b.x >> 16) | (b.y & 0xffff0000u);
                    al.d[3] = (b.z >> 16) | (b.w & 0xffff0000u);
                    acc0 = __builtin_amdgcn_mfma_f32_16x16x32_bf16(ah.v, Bf[ks], acc0, 0, 0, 0);
                    acc1 = __builtin_amdgcn_mfma_f32_16x16x32_bf16(al.v, Bf[ks], acc1, 0, 0, 0);
                }
            }
        }
        if (wv < 3) {
            f32x4 at = acc0 + acc1;
            const int cb0 = wv * 256 + ((lane >> 4) * 4) * 16 + (lane & 15);
            GHL[cb0]      = at[0];
            GHL[cb0 + 16] = at[1];
            GHL[cb0 + 32] = at[2];
            GHL[cb0 + 48] = at[3];
        }
        __syncthreads();

        float ghr = GHL[tid];
        float ghz = GHL[256 + tid];
        float ghg = GHL[512 + tid];
        float r = sigf(gi0 + bihr + ghr + bhhr);
        float z = sigf(gi1 + bihz + ghz + bhhz);
        float g = tanhf(gi2 + bihg + r * (ghg + bhhg));
        float hn = (1.f - z) * g + z * hp;
        hp = hn;
        hist[((size_t)tt * BB + ub) * HH + uj] = hn;
        bf16 hi = (bf16)hn;
        bf16 lo = (bf16)(hn - (float)hi);
        unsigned int pk = (unsigned int)__builtin_bit_cast(unsigned short, hi)
                        | ((unsigned int)__builtin_bit_cast(unsigned short, lo) << 16);
        unsigned int* hw = hbuf + ((size_t)tt * BB + ub) * KP + uj;
        asm volatile("global_store_dword %0, %1, off sc0 sc1" :: "v"(hw), "v"(pk) : "memory");

        asm volatile("s_waitcnt vmcnt(0)" ::: "memory");
        __syncthreads();
        if (tid == 0) {
            unsigned int one = 1u;
            unsigned int* fw = flags + ((size_t)dir * TE + s) * 32 + blk;
            asm volatile("global_store_dword %0, %1, off sc0 sc1" :: "v"(fw), "v"(one) : "memory");
        }
    }
}

__global__ void combine_enc(const float* __restrict__ hf, const float* __restrict__ hb,
                            float* __restrict__ enc_out) {
    int idx = blockIdx.x * blockDim.x + threadIdx.x;
    if (idx >= BB * TE * HH) return;
    int hcol = idx % HH;
    int t = (idx / HH) % TE;
    int b = idx / (HH * TE);
    size_t src = ((size_t)t * BB + b) * HH + hcol;
    enc_out[idx] = hf[src] + hb[src];
}

__global__ void init_hdec2(const float* __restrict__ hf, const float* __restrict__ hb,
                           float* __restrict__ hdec, bf16* __restrict__ h2b) {
    int idx = blockIdx.x * blockDim.x + threadIdx.x;
    if (idx >= SBN * HH) return;
    int hcol = idx % HH;
    int n = idx / HH;
    int b = n & 15;
    float v = hf[((size_t)(TE - 1) * BB + b) * HH + hcol] + hb[((size_t)b) * HH + hcol];
    hdec[idx] = v;
    h2b[(size_t)n * KP + hcol] = (bf16)v;
}

__global__ void gru_dec2(const float* __restrict__ gi, const float* __restrict__ gh,
                         const float* __restrict__ bih, const float* __restrict__ bhh,
                         const float* __restrict__ hprev, float* __restrict__ hnew,
                         bf16* __restrict__ h2b) {
    int idx = blockIdx.x * blockDim.x + threadIdx.x;
    if (idx >= SBN * HH) return;
    int n = idx / HH, j = idx % HH;
    const float* gir = gi + (size_t)n * H3P;
    const float* ghr = gh + (size_t)n * H3P;
    float r = sigf(gir[j] + bih[j] + ghr[j] + bhh[j]);
    float z = sigf(gir[HH + j] + bih[HH + j] + ghr[HH + j] + bhh[HH + j]);
    float g = tanhf(gir[2 * HH + j] + bih[2 * HH + j] + r * (ghr[2 * HH + j] + bhh[2 * HH + j]));
    float hn = (1.f - z) * g + z * hprev[idx];
    hnew[idx] = hn;
    h2b[(size_t)n * KP + j] = (bf16)hn;
}

// ---------------- bulk attention (unchanged) ----------------
__global__ __launch_bounds__(256) void attn3(
    const float* __restrict__ hfall,
    const float* __restrict__ enc,
    const float* __restrict__ decxf,
    const float* __restrict__ Wr, const float* __restrict__ br,
    const float* __restrict__ Wg, const float* __restrict__ bg,
    float* __restrict__ probw,
    float* __restrict__ sww,
    float* __restrict__ outg) {
    const int b = blockIdx.x >> 1;
    const int half = blockIdx.x & 1;
    const int td = blockIdx.y;
    const int s0 = half * 15;
    const int tid = threadIdx.x;
    const int lane = tid & 63, wv = tid >> 6;

    __shared__ __align__(16) float h2L[15][HH];
    __shared__ __align__(16) float scL[15][TE];
    __shared__ __align__(16) float cxL[15][HH];

    const float* h2base = hfall + (size_t)(td + 1) * SBN * HH;
    for (int i = tid; i < 15 * HH; i += 256) {
        int j = i / HH, k = i % HH;
        int n = (s0 + j) * BB + b;
        h2L[j][k] = h2base[(size_t)n * HH + k];
    }
    __syncthreads();

    {
        float acc[15];
#pragma unroll
        for (int j = 0; j < 15; ++j) acc[j] = 0.f;
        const float4* er = (const float4*)(enc + ((size_t)b * TE + tid) * HH);
        for (int k4 = 0; k4 < HH / 4; ++k4) {
            float4 e = er[k4];
#pragma unroll
            for (int j = 0; j < 15; ++j) {
                float4 hv = *(const float4*)(&h2L[j][k4 * 4]);
                acc[j] += e.x * hv.x + e.y * hv.y + e.z * hv.z + e.w * hv.w;
            }
        }
#pragma unroll
        for (int j = 0; j < 15; ++j) scL[j][tid] = acc[j];
    }
    __syncthreads();

    for (int j = wv; j < 15; j += 4) {
        float v0 = scL[j][lane], v1 = scL[j][lane + 64];
        float v2 = scL[j][lane + 128], v3 = scL[j][lane + 192];
        float m = fmaxf(fmaxf(v0, v1), fmaxf(v2, v3));
        for (int d = 32; d; d >>= 1) m = fmaxf(m, __shfl_xor(m, d));
        v0 = __expf(v0 - m); v1 = __expf(v1 - m);
        v2 = __expf(v2 - m); v3 = __expf(v3 - m);
        float s = v0 + v1 + v2 + v3;
        for (int d = 32; d; d >>= 1) s += __shfl_xor(s, d);
        float inv = 1.f / s;
        scL[j][lane]       = v0 * inv;
        scL[j][lane + 64]  = v1 * inv;
        scL[j][lane + 128] = v2 * inv;
        scL[j][lane + 192] = v3 * inv;
    }
    __syncthreads();

    for (int i = tid; i < 15 * TE; i += 256) {
        int j = i / TE, t = i % TE;
        int n = (s0 + j) * BB + b;
        probw[((size_t)td * SBN + n) * TE + t] = scL[j][t];
    }

    {
        float cx0[15], cx1[15];
#pragma unroll
        for (int j = 0; j < 15; ++j) { cx0[j] = 0.f; cx1[j] = 0.f; }
        const int c0 = tid, c1 = tid + 256;
        const bool has2 = (c1 < HH);
        for (int t = 0; t < TE; t += 2) {
            const float* e0r = enc + ((size_t)b * TE + t) * HH;
            const float* e1r = e0r + HH;
            float e00 = e0r[c0], e01 = e1r[c0];
            float e10 = 0.f, e11 = 0.f;
            if (has2) { e10 = e0r[c1]; e11 = e1r[c1]; }
#pragma unroll
            for (int j = 0; j < 15; ++j) {
                float2 p = *(const float2*)(&scL[j][t]);
                cx0[j] += p.x * e00 + p.y * e01;
                cx1[j] += p.x * e10 + p.y * e11;
            }
        }
#pragma unroll
        for (int j = 0; j < 15; ++j) {
            cxL[j][c0] = cx0[j];
            if (has2) cxL[j][c1] = cx1[j];
        }
    }
    __syncthreads();

    for (int j = wv; j < 15; j += 4) {
        int n = (s0 + j) * BB + b;
        const float* dx = decxf + ((size_t)td * SBN + n) * HH;
        float a = 0.f;
        for (int k = lane; k < H3; k += 64) {
            float v = (k < HH) ? h2L[j][k]
                    : (k < 2 * HH) ? cxL[j][k - HH]
                    : dx[k - 2 * HH];
            a += v * Wr[k];
        }
        for (int d = 32; d; d >>= 1) a += __shfl_xor(a, d);
        if (lane == 0) sww[(size_t)td * SBN + n] = sigf(a + br[0]);
    }

    if (td == 0) {
        for (int j = wv; j < 15; j += 4) {
            int n = (s0 + j) * BB + b;
#pragma unroll
            for (int g = 0; g < GGN; ++g) {
                float a = 0.f;
                for (int k = lane; k < HH; k += 64) a += cxL[j][k] * Wg[g * HH + k];
                for (int d = 32; d; d >>= 1) a += __shfl_xor(a, d);
                if (lane == 0) outg[n * GGN + g] = a + bg[g];
            }
        }
    }
}

// softmax over vocab (bf16 logits) + final write + fused pointer scatter.
__global__ __launch_bounds__(1024) void smax_scatter3(
    const bf16* __restrict__ logitsH, const float* __restrict__ sw,
    const int* __restrict__ story, const float* __restrict__ probw,
    float* __restrict__ out, int td0) {
    int n = blockIdx.x, tid = threadIdx.x;
    int td = td0 + blockIdx.y;
    const bf16* lrow = logitsH + ((size_t)blockIdx.y * MP_DEC + n) * VP;
    const float* prow = probw + ((size_t)td * SBN + n) * TE;
    float swv = sw[(size_t)td * SBN + n];
    __shared__ float red[16];
    __shared__ float bc[2];
    float v[18];
    float mx = -1e30f;
#pragma unroll
    for (int i = 0; i < 18; ++i) {
        int c = tid + (i << 10);
        v[i] = (c < VV) ? (float)lrow[c] : -1e30f;
        mx = fmaxf(mx, v[i]);
    }
    for (int d = 32; d; d >>= 1) mx = fmaxf(mx, __shfl_xor(mx, d));
    if ((tid & 63) == 0) red[tid >> 6] = mx;
    __syncthreads();
    if (tid == 0) {
        float m2 = red[0];
        for (int w = 1; w < 16; ++w) m2 = fmaxf(m2, red[w]);
        bc[0] = m2;
    }
    __syncthreads();
    mx = bc[0];
    float s = 0.f;
#pragma unroll
    for (int i = 0; i < 18; ++i) {
        int c = tid + (i << 10);
        if (c < VV) { v[i] = __expf(v[i] - mx); s += v[i]; }
    }
    for (int d = 32; d; d >>= 1) s += __shfl_xor(s, d);
    if ((tid & 63) == 0) red[tid >> 6] = s;
    __syncthreads();
    if (tid == 0) {
        float s2 = 0.f;
        for (int w = 0; w < 16; ++w) s2 += red[w];
        bc[1] = s2;
    }
    __syncthreads();
    float scale = swv / bc[1];
    float* orow = out + ((size_t)n * TDN + td) * VV;
#pragma unroll
    for (int i = 0; i < 18; ++i) {
        int c = tid + (i << 10);
        if (c < VV) orow[c] = v[i] * scale;
    }
    __syncthreads();
    if (tid < TE) {
        int b = n & 15;
        int tok = story[b * TE + tid];
        float val = (1.f - swv) * prow[tid];
        atomicAdd(orow + tok, val);
    }
}

static inline int cdiv(long long a, long long b) { return (int)((a + b - 1) / b); }

extern "C" void kernel_launch(void* const* d_in, const int* in_sizes, int n_in,
                              void* d_out, int out_size, void* d_ws, size_t ws_size,
                              hipStream_t stream) {
    const int*   story  = (const int*)d_in[0];
    const int*   target = (const int*)d_in[1];
    const float* emb    = (const float*)d_in[2];
    const float* wih_f  = (const float*)d_in[3];
    const float* whh_f  = (const float*)d_in[4];
    const float* bih_f  = (const float*)d_in[5];
    const float* bhh_f  = (const float*)d_in[6];
    const float* wih_b  = (const float*)d_in[7];
    const float* whh_b  = (const float*)d_in[8];
    const float* bih_b  = (const float*)d_in[9];
    const float* bhh_b  = (const float*)d_in[10];
    const float* dwih   = (const float*)d_in[11];
    const float* dwhh   = (const float*)d_in[12];
    const float* dbih   = (const float*)d_in[13];
    const float* dbhh   = (const float*)d_in[14];
    const float* wr     = (const float*)d_in[15];
    const float* brr    = (const float*)d_in[16];
    const float* wgg    = (const float*)d_in[17];
    const float* bgg    = (const float*)d_in[18];
    const float* slot   = (const float*)d_in[19];
    float* out = (float*)d_out;

    char* wsb = (char*)d_ws;
    size_t off = 0;
    auto alloc = [&](size_t bytes) -> char* {
        char* p = wsb + off;
        off = (off + bytes + 255) & ~(size_t)255;
        return p;
    };
    bf16*  embb  = (bf16*)alloc((size_t)VP * KP * 2);
    bf16*  aenc  = (bf16*)alloc((size_t)NROW_ENC * KP * 2);
    bf16*  wfb   = (bf16*)alloc((size_t)H3P * KP * 2);
    bf16*  wbb   = (bf16*)alloc((size_t)H3P * KP * 2);
    bf16*  dwihb = (bf16*)alloc((size_t)H3P * KP * 2);
    bf16*  dwhhb = (bf16*)alloc((size_t)H3P * KP * 2);
    bf16*  decxb = (bf16*)alloc((size_t)TDN * SBN * KP * 2);
    bf16*  h2ball= (bf16*)alloc((size_t)9 * MP_DEC * KP * 2);
    unsigned int* hbuff = (unsigned int*)alloc((size_t)TE * BB * KP * 4);
    unsigned int* hbufb = (unsigned int*)alloc((size_t)TE * BB * KP * 4);
    unsigned int* flags = (unsigned int*)alloc((size_t)2 * TE * 32 * 4);
    float* gif   = (float*)alloc((size_t)NROW_ENC * H3P * 4);
    float* gib   = (float*)alloc((size_t)NROW_ENC * H3P * 4);
    float* gidec = (float*)alloc((size_t)TDN * SBN * H3P * 4);
    float* ghdec = (float*)alloc((size_t)MP_DEC * H3P * 4);
    float* histf = (float*)alloc((size_t)TE * BB * HH * 4);
    float* histb = (float*)alloc((size_t)TE * BB * HH * 4);
    float* encout= (float*)alloc((size_t)BB * TE * HH * 4);
    float* decxf = (float*)alloc((size_t)TDN * SBN * HH * 4);
    float* hfall = (float*)alloc((size_t)9 * SBN * HH * 4);
    float* probw = (float*)alloc((size_t)TDN * SBN * TE * 4);
    float* sww   = (float*)alloc((size_t)TDN * SBN * 4);
    bf16*  logitsH = (bf16*)alloc((size_t)MP_DEC * VP * 2);
    const size_t bigBytes = (size_t)TDN * MP_DEC * VP * 2;
    bf16* logitsAllH = nullptr;
    if (off + bigBytes + 256 <= ws_size) logitsAllH = (bf16*)alloc(bigBytes);
    (void)in_sizes; (void)n_in; (void)out_size;

    (void)hipMemsetAsync(flags, 0, (size_t)2 * TE * 32 * 4, stream);

    const int thr = 256;
    prep_aenc<<<cdiv((long long)NROW_ENC * KP, thr), thr, 0, stream>>>(story, emb, aenc);
    {
        dim3 g(cdiv((long long)H3P * KP, thr), 4);
        prep_wpad4<<<g, thr, 0, stream>>>(wih_f, wih_b, dwih, dwhh, wfb, wbb, dwihb, dwhhb);
    }
    prep_decx<<<cdiv((long long)TDN * SBN * KP, thr), thr, 0, stream>>>(target, emb, slot, decxf, decxb);
    zero_bf16k<<<cdiv((long long)9 * MP_DEC * KP, thr), thr, 0, stream>>>(h2ball, (size_t)9 * MP_DEC * KP);

    {
        dim3 g(NROW_ENC / 128, H3P / 128, 2);
        gemm_gi<<<g, 256, 0, stream>>>(aenc, wfb, wbb, gif, gib);
    }

    enc_fat<<<2 * EBLK + GIDEC_TILES + EMBB_BLKS, 256, 0, stream>>>(
        gif, gib, whh_f, whh_b, bih_f, bhh_f, bih_b, bhh_b,
        histf, histb, hbuff, hbufb, flags,
        decxb, dwihb, gidec, emb, embb);

    combine_enc<<<cdiv((long long)BB * TE * HH, thr), thr, 0, stream>>>(histf, histb, encout);
    init_hdec2<<<cdiv((long long)SBN * HH, thr), thr, 0, stream>>>(histf, histb, hfall, h2ball);

    // phase 1: decoder h-chain (proven 16-launch form)
    for (int td = 0; td < TDN; ++td) {
        dim3 g(MP_DEC / 128, H3P / 128);
        gemm_bt<<<g, 256, 0, stream>>>(h2ball + (size_t)td * MP_DEC * KP, dwhhb, ghdec, nullptr,
                                       MP_DEC, H3P, KP);
        gru_dec2<<<cdiv((long long)SBN * HH, thr), thr, 0, stream>>>(
            gidec + (size_t)td * SBN * H3P, ghdec, dbih, dbhh,
            hfall + (size_t)td * SBN * HH,
            hfall + (size_t)(td + 1) * SBN * HH,
            h2ball + (size_t)(td + 1) * MP_DEC * KP);
    }

    // phase 3a: batched logits GEMM first (4512 blocks), attn3 backfills its tail
    if (logitsAllH) {
        dim3 g((TDN * MP_DEC) / 128, VP / 128);
        gemm_bt<<<g, 256, 0, stream>>>(h2ball + (size_t)MP_DEC * KP, embb, nullptr, logitsAllH,
                                       TDN * MP_DEC, VP, KP);
        {
            dim3 ga(32, TDN);
            attn3<<<ga, 256, 0, stream>>>(hfall, encout, decxf, wr, brr, wgg, bgg,
                                          probw, sww, out + (size_t)SBN * TDN * VV);
        }
        dim3 gs(SBN, TDN);
        smax_scatter3<<<gs, 1024, 0, stream>>>(logitsAllH, sww, story, probw, out, 0);
    } else {
        {
            dim3 ga(32, TDN);
            attn3<<<ga, 256, 0, stream>>>(hfall, encout, decxf, wr, brr, wgg, bgg,
                                          probw, sww, out + (size_t)SBN * TDN * VV);
        }
        for (int td = 0; td < TDN; ++td) {
            dim3 g(MP_DEC / 128, VP / 128);
            gemm_bt<<<g, 256, 0, stream>>>(h2ball + (size_t)(td + 1) * MP_DEC * KP, embb,
                                           nullptr, logitsH, MP_DEC, VP, KP);
            dim3 gs(SBN, 1);
            smax_scatter3<<<gs, 1024, 0, stream>>>(logitsH, sww, story, probw, out, td);
        }
    }
}